// Round 5
// baseline (361.600 us; speedup 1.0000x reference)
//
#include <hip/hip_runtime.h>
#include <math.h>

#define NT   16384
#define KD   2048
#define PROJ 256
#define NH   4
#define HD   64
#define NE   64

#define GATES_OFF 0
#define IDX_OFF   (NT * NE)            // 1048576
#define GL_OFF    (NT * NE + NT * 2)   // 1081344

// ---------------------------------------------------------------------------
// K1: partial[kh][c][tok] = sum_{k in half kh} x[tok][k] * Wp[k][c]
// ONE WAVE per block (64 thr), tile 64m x 64n, BK=16, per-thread 8m x 8n
// (64 FMA : 2 ds_read_b128 per kk). Split-K=2 -> grid (256,4,2)=2048 blocks
// = 8 waves/CU. A staged in double-buffered LDS (k-major, pad 66) with NO
// barriers (single-wave LDS ops are in-order); B read per-kk from global
// (L1/L2-resident Wp) on the vmem pipe. Accum folded every 512 k.
// ---------------------------------------------------------------------------
#define K1_BK 16

__global__ __launch_bounds__(64, 2) void k1_gemm(const float* __restrict__ x,
                                                 const float* __restrict__ Wp,
                                                 float* __restrict__ part)
{
    __shared__ float As[2][K1_BK][66];   // 8.4 KB; k-major, pad 66

    const int t  = threadIdx.x;          // 0..63
    const int ng = t & 7;                // n: c = n0 + ng*8 + j
    const int mg = t >> 3;               // m: tok = m0 + mg*8 + i
    const int m0 = blockIdx.x * 64;
    const int n0 = blockIdx.y * 64;
    const int kb = blockIdx.z * (KD / 2);    // k-half base

    const float* xa = &x[(size_t)(m0 + t) * KD + kb];       // lane t owns row t
    const float* wb = &Wp[(size_t)kb * PROJ + n0 + ng * 8];

    float4 pa0 = *(const float4*)(xa + 0);
    float4 pa1 = *(const float4*)(xa + 4);
    float4 pa2 = *(const float4*)(xa + 8);
    float4 pa3 = *(const float4*)(xa + 12);

    float acc[8][8], accT[8][8];
#pragma unroll
    for (int i = 0; i < 8; ++i)
#pragma unroll
        for (int j = 0; j < 8; ++j) { acc[i][j] = 0.f; accT[i][j] = 0.f; }

    const int NTILE = (KD / 2) / K1_BK;  // 64
    for (int ti = 0; ti < NTILE; ++ti) {
        const int buf = ti & 1;
        // ---- stage A tile (regs -> LDS, k-major scalar writes, 2-way banks)
        As[buf][ 0][t] = pa0.x; As[buf][ 1][t] = pa0.y;
        As[buf][ 2][t] = pa0.z; As[buf][ 3][t] = pa0.w;
        As[buf][ 4][t] = pa1.x; As[buf][ 5][t] = pa1.y;
        As[buf][ 6][t] = pa1.z; As[buf][ 7][t] = pa1.w;
        As[buf][ 8][t] = pa2.x; As[buf][ 9][t] = pa2.y;
        As[buf][10][t] = pa2.z; As[buf][11][t] = pa2.w;
        As[buf][12][t] = pa3.x; As[buf][13][t] = pa3.y;
        As[buf][14][t] = pa3.z; As[buf][15][t] = pa3.w;
        // ---- prefetch next A tile (no barrier: single-wave, in-order LDS)
        if (ti + 1 < NTILE) {
            const float* xn = xa + (ti + 1) * K1_BK;
            pa0 = *(const float4*)(xn + 0);
            pa1 = *(const float4*)(xn + 4);
            pa2 = *(const float4*)(xn + 8);
            pa3 = *(const float4*)(xn + 12);
        }
        // ---- compute: B straight from global (L1-hot), A from LDS
        const float* wbt = wb + (size_t)ti * K1_BK * PROJ;
#pragma unroll
        for (int kk = 0; kk < K1_BK; ++kk) {
            const float4 b0 = *(const float4*)&wbt[(size_t)kk * PROJ];
            const float4 b1 = *(const float4*)&wbt[(size_t)kk * PROJ + 4];
            const float4 a0 = *(const float4*)&As[buf][kk][mg * 8];
            const float4 a1 = *(const float4*)&As[buf][kk][mg * 8 + 4];
            const float av[8] = { a0.x, a0.y, a0.z, a0.w, a1.x, a1.y, a1.z, a1.w };
            const float bv[8] = { b0.x, b0.y, b0.z, b0.w, b1.x, b1.y, b1.z, b1.w };
#pragma unroll
            for (int i = 0; i < 8; ++i)
#pragma unroll
                for (int j = 0; j < 8; ++j)
                    acc[i][j] = fmaf(av[i], bv[j], acc[i][j]);
        }
        if ((ti & 31) == 31) {           // fold every 512 k (rounding profile)
#pragma unroll
            for (int i = 0; i < 8; ++i)
#pragma unroll
                for (int j = 0; j < 8; ++j) { accT[i][j] += acc[i][j]; acc[i][j] = 0.f; }
        }
    }

    // ---- store partials channel-major: part[kh][c][tok]
    float* pbase = part + (size_t)blockIdx.z * PROJ * NT;
#pragma unroll
    for (int j = 0; j < 8; ++j) {
        float4 lo = { accT[0][j], accT[1][j], accT[2][j], accT[3][j] };
        float4 hi = { accT[4][j], accT[5][j], accT[6][j], accT[7][j] };
        float* dst = &pbase[(size_t)(n0 + ng * 8 + j) * NT + m0 + mg * 8];
        *(float4*)&dst[0] = lo;
        *(float4*)&dst[4] = hi;
    }
}

// ---------------------------------------------------------------------------
// K1b: hT[c][tok] = part0 + part1 + bp[c]   (in-place into part0 slot)
// ---------------------------------------------------------------------------
__global__ __launch_bounds__(256) void k1_reduce(float* __restrict__ hT,
                                                 const float* __restrict__ part1,
                                                 const float* __restrict__ bp)
{
    const size_t i4 = (size_t)blockIdx.x * 256 + threadIdx.x;  // float4 index
    const int c = (int)((i4 * 4) >> 14);                       // /NT
    const float b = bp[c];
    float4 a = *(const float4*)&hT[i4 * 4];
    const float4 d = *(const float4*)&part1[i4 * 4];
    a.x += d.x + b; a.y += d.y + b; a.z += d.z + b; a.w += d.w + b;
    *(float4*)&hT[i4 * 4] = a;
}

// ---------------------------------------------------------------------------
// K2: per head: hid = relu(h @ W1 + b1); hl = hid @ W2 + b2  (both 64x64 GEMMs)
// Channel-major h_T / hl_T. 256 thr, 128 tokens, one head. Per-thread
// 4e x 8tok; W1/W2 in LDS; hid tile through padded LDS; B-frags = global f4.
// ---------------------------------------------------------------------------
__global__ __launch_bounds__(256) void k2_heads(const float* __restrict__ hT,
                                                const float* __restrict__ W1,
                                                const float* __restrict__ b1,
                                                const float* __restrict__ W2,
                                                const float* __restrict__ b2,
                                                float* __restrict__ hlT)
{
    __shared__ float W1s[64][64];
    __shared__ float W2s[64][64];
    __shared__ float Hs[64][132];     // hid tile [d2][tok], pad 132

    const int t    = threadIdx.x;
    const int eg   = t & 15;          // e-group: e = eg*4 + j
    const int tg   = t >> 4;          // tok-group: tok = tok0 + tg*8 + i
    const int head = blockIdx.y;
    const int tok0 = blockIdx.x * 128;

    {   // stage weights (coalesced float4)
        const float4* g1 = (const float4*)(W1 + (size_t)head * HD * HD);
        const float4* g2 = (const float4*)(W2 + (size_t)head * HD * HD);
        float4* s1 = (float4*)&W1s[0][0];
        float4* s2 = (float4*)&W2s[0][0];
#pragma unroll
        for (int q = 0; q < 4; ++q) {
            s1[t + q * 256] = g1[t + q * 256];
            s2[t + q * 256] = g2[t + q * 256];
        }
    }
    const float4 b1v = *(const float4*)&b1[head * HD + eg * 4];
    const float4 b2v = *(const float4*)&b2[head * HD + eg * 4];
    __syncthreads();

    // ---- stage 1: hid[e][tok] = relu(b1 + sum_d h_T[head*64+d][tok]*W1[d][e])
    float acc[4][8];
    {
        const float bb[4] = { b1v.x, b1v.y, b1v.z, b1v.w };
#pragma unroll
        for (int j = 0; j < 4; ++j)
#pragma unroll
            for (int i = 0; i < 8; ++i) acc[j][i] = bb[j];
    }
    const float* hbase = &hT[(size_t)(head * HD) * NT + tok0 + tg * 8];
#pragma unroll 4
    for (int d = 0; d < HD; ++d) {
        const float4 w  = *(const float4*)&W1s[d][eg * 4];
        const float4 h0 = *(const float4*)&hbase[(size_t)d * NT];
        const float4 h1 = *(const float4*)&hbase[(size_t)d * NT + 4];
        const float wv[4] = { w.x, w.y, w.z, w.w };
        const float hv[8] = { h0.x, h0.y, h0.z, h0.w, h1.x, h1.y, h1.z, h1.w };
#pragma unroll
        for (int j = 0; j < 4; ++j)
#pragma unroll
            for (int i = 0; i < 8; ++i)
                acc[j][i] = fmaf(wv[j], hv[i], acc[j][i]);
    }
#pragma unroll
    for (int j = 0; j < 4; ++j) {
        float4 lo, hi;
        lo.x = fmaxf(acc[j][0], 0.f); lo.y = fmaxf(acc[j][1], 0.f);
        lo.z = fmaxf(acc[j][2], 0.f); lo.w = fmaxf(acc[j][3], 0.f);
        hi.x = fmaxf(acc[j][4], 0.f); hi.y = fmaxf(acc[j][5], 0.f);
        hi.z = fmaxf(acc[j][6], 0.f); hi.w = fmaxf(acc[j][7], 0.f);
        *(float4*)&Hs[eg * 4 + j][tg * 8]     = lo;
        *(float4*)&Hs[eg * 4 + j][tg * 8 + 4] = hi;
    }
    __syncthreads();

    // ---- stage 2: hl[e][tok] = b2 + sum_d2 Hs[d2][tok]*W2[d2][e]
    {
        const float bb[4] = { b2v.x, b2v.y, b2v.z, b2v.w };
#pragma unroll
        for (int j = 0; j < 4; ++j)
#pragma unroll
            for (int i = 0; i < 8; ++i) acc[j][i] = bb[j];
    }
#pragma unroll 4
    for (int d = 0; d < HD; ++d) {
        const float4 w  = *(const float4*)&W2s[d][eg * 4];
        const float4 h0 = *(const float4*)&Hs[d][tg * 8];
        const float4 h1 = *(const float4*)&Hs[d][tg * 8 + 4];
        const float wv[4] = { w.x, w.y, w.z, w.w };
        const float hv[8] = { h0.x, h0.y, h0.z, h0.w, h1.x, h1.y, h1.z, h1.w };
#pragma unroll
        for (int j = 0; j < 4; ++j)
#pragma unroll
            for (int i = 0; i < 8; ++i)
                acc[j][i] = fmaf(wv[j], hv[i], acc[j][i]);
    }
#pragma unroll
    for (int j = 0; j < 4; ++j) {
        float4 lo = { acc[j][0], acc[j][1], acc[j][2], acc[j][3] };
        float4 hi = { acc[j][4], acc[j][5], acc[j][6], acc[j][7] };
        float* dst = &hlT[(size_t)(head * HD + eg * 4 + j) * NT + tok0 + tg * 8];
        *(float4*)&dst[0] = lo;
        *(float4*)&dst[4] = hi;
    }
}

// ---------------------------------------------------------------------------
// K3: gl[tok][e] = (hl_T[:, tok] . Wc[:, e] + bc[e]) / clip(T); top-2 softmax.
// 512 thr, 64 tokens/block, per-thread 4e x 2tok. No LDS; Wc L1/L2-resident.
// ---------------------------------------------------------------------------
__global__ __launch_bounds__(512) void k3_gate(const float* __restrict__ hlT,
                                               const float* __restrict__ Wc,
                                               const float* __restrict__ bc,
                                               const float* __restrict__ temp,
                                               float* __restrict__ out)
{
    const int t    = threadIdx.x;
    const int eg   = t & 15;          // e = eg*4 + j  (low lane bits -> shfl ok)
    const int tg   = t >> 4;          // 0..31: tok = tok0 + tg*2 + i
    const int tok0 = blockIdx.x * 64;

    const float tv  = fminf(fmaxf(temp[0], 0.5f), 5.0f);
    const float inv = 1.0f / tv;      // uniform scale: ordering identical to /tv
    const float4 bcv = *(const float4*)&bc[eg * 4];

    float acc[4][2];
    acc[0][0] = bcv.x; acc[0][1] = bcv.x;
    acc[1][0] = bcv.y; acc[1][1] = bcv.y;
    acc[2][0] = bcv.z; acc[2][1] = bcv.z;
    acc[3][0] = bcv.w; acc[3][1] = bcv.w;

    const float* hb = &hlT[tok0 + tg * 2];
#pragma unroll 8
    for (int k = 0; k < PROJ; ++k) {
        const float2 hv = *(const float2*)&hb[(size_t)k * NT];
        const float4 wv = *(const float4*)&Wc[k * NE + eg * 4];
        const float wa[4] = { wv.x, wv.y, wv.z, wv.w };
#pragma unroll
        for (int j = 0; j < 4; ++j) {
            acc[j][0] = fmaf(wa[j], hv.x, acc[j][0]);
            acc[j][1] = fmaf(wa[j], hv.y, acc[j][1]);
        }
    }

#pragma unroll
    for (int i = 0; i < 2; ++i) {
        const int tok = tok0 + tg * 2 + i;
        float gl_[4];
#pragma unroll
        for (int j = 0; j < 4; ++j) gl_[j] = acc[j][i] * inv;

        // top-1 (strict > keeps lowest index; cross-lane ties -> lower index)
        float v1 = gl_[0]; int i1 = eg * 4;
#pragma unroll
        for (int j = 1; j < 4; ++j)
            if (gl_[j] > v1) { v1 = gl_[j]; i1 = eg * 4 + j; }
#pragma unroll
        for (int off = 8; off >= 1; off >>= 1) {
            const float ov = __shfl_xor(v1, off);
            const int   oi = __shfl_xor(i1, off);
            if (ov > v1 || (ov == v1 && oi < i1)) { v1 = ov; i1 = oi; }
        }
        // top-2: exclude winner
        float v2 = -INFINITY; int i2 = NE;
#pragma unroll
        for (int j = 0; j < 4; ++j) {
            const int e = eg * 4 + j;
            if (e != i1 && gl_[j] > v2) { v2 = gl_[j]; i2 = e; }
        }
#pragma unroll
        for (int off = 8; off >= 1; off >>= 1) {
            const float ov = __shfl_xor(v2, off);
            const int   oi = __shfl_xor(i2, off);
            if (ov > v2 || (ov == v2 && oi < i2)) { v2 = ov; i2 = oi; }
        }

        const float e2  = expf(v2 - v1);
        const float s   = 1.f + e2;
        const float g1v = 1.f / s;
        const float g2v = e2 / s;

        float4 gv;
        {
            const int e0 = eg * 4;
            gv.x = (e0 + 0 == i1) ? g1v : ((e0 + 0 == i2) ? g2v : 0.f);
            gv.y = (e0 + 1 == i1) ? g1v : ((e0 + 1 == i2) ? g2v : 0.f);
            gv.z = (e0 + 2 == i1) ? g1v : ((e0 + 2 == i2) ? g2v : 0.f);
            gv.w = (e0 + 3 == i1) ? g1v : ((e0 + 3 == i2) ? g2v : 0.f);
        }
        *(float4*)&out[GATES_OFF + (size_t)tok * NE + eg * 4] = gv;
        const float4 glv = { gl_[0], gl_[1], gl_[2], gl_[3] };
        *(float4*)&out[GL_OFF + (size_t)tok * NE + eg * 4] = glv;
        if (eg == 0) {
            out[IDX_OFF + (size_t)tok * 2 + 0] = (float)i1;
            out[IDX_OFF + (size_t)tok * 2 + 1] = (float)i2;
        }
    }
}

// ---------------------------------------------------------------------------
extern "C" void kernel_launch(void* const* d_in, const int* in_sizes, int n_in,
                              void* d_out, int out_size, void* d_ws, size_t ws_size,
                              hipStream_t stream)
{
    (void)in_sizes; (void)n_in; (void)out_size; (void)ws_size;

    const float* x    = (const float*)d_in[0];
    const float* Wp   = (const float*)d_in[1];
    const float* bp   = (const float*)d_in[2];
    const float* W1   = (const float*)d_in[3];
    const float* b1   = (const float*)d_in[4];
    const float* W2   = (const float*)d_in[5];
    const float* b2   = (const float*)d_in[6];
    const float* Wc   = (const float*)d_in[7];
    const float* bc   = (const float*)d_in[8];
    const float* temp = (const float*)d_in[9];

    float* out  = (float*)d_out;
    float* hT   = (float*)d_ws;                    // part0, then hT  (16.8 MB)
    float* hlT  = hT + (size_t)PROJ * NT;          // part1, then hlT (16.8 MB)

    // k1 partials: part[z][c][tok], z=0 -> hT slot, z=1 -> hlT slot
    k1_gemm  <<<dim3(NT / 64, PROJ / 64, 2), 64, 0, stream>>>(x, Wp, hT);
    k1_reduce<<<dim3(PROJ * NT / 4 / 256),  256, 0, stream>>>(hT, hlT, bp);
    k2_heads <<<dim3(NT / 128, NH),         256, 0, stream>>>(hT, W1, b1, W2, b2, hlT);
    k3_gate  <<<dim3(NT / 64),              512, 0, stream>>>(hlT, Wc, bc, temp, out);
}

// Round 6
// 320.597 us; speedup vs baseline: 1.1279x; 1.1279x over previous
//
#include <hip/hip_runtime.h>
#include <math.h>

#define NT   16384
#define KD   2048
#define PROJ 256
#define NH   4
#define HD   64
#define NE   64

#define GATES_OFF 0
#define IDX_OFF   (NT * NE)            // 1048576
#define GL_OFF    (NT * NE + NT * 2)   // 1081344

// ---------------------------------------------------------------------------
// K1: h_T[c][tok] = sum_k x[tok][k] * Wp[k][c] + bp[c]   (channel-major out)
// Tile 128m x 64n, BK=16, 128 thr (2 waves); per-thread 8m x 8n
// (64 FMA : 4 ds_read_b128 per kk -> per-CU LDS 152 cyc vs per-SIMD VALU 128).
// Grid (128,4) = 512 blocks ~ 2 blocks/CU = 4 waves/CU (1/SIMD).
// Double-buffered LDS, ONE barrier per k-tile, register prefetch.
// ---------------------------------------------------------------------------
#define K1_BK 16

__global__ __launch_bounds__(128) void k1_gemm(const float* __restrict__ x,
                                               const float* __restrict__ Wp,
                                               const float* __restrict__ bp,
                                               float* __restrict__ hT)
{
    __shared__ float As[2][K1_BK][132];   // 16.9 KB, k-major, pad 132 (2-way max)
    __shared__ float Bs[2][K1_BK][68];    //  8.7 KB, pad 68

    const int t  = threadIdx.x;           // 0..127
    const int ng = t & 7;                 // n: c = n0 + ng*8 + j
    const int mg = t >> 3;                // m: tok = m0 + mg*8 + i (0..15)
    const int m0 = blockIdx.x * 128;
    const int n0 = blockIdx.y * 64;

    // staging decomposition
    const int bkr = t >> 3;               // B k-row 0..15
    const int bnq = (t & 7) * 8;          // B n offset {0,8,...,56}

    const float* xa = &x[(size_t)(m0 + t) * KD];            // lane t owns row t
    const float* wb = &Wp[(size_t)bkr * PROJ + n0 + bnq];

    float4 pa0 = *(const float4*)(xa + 0);
    float4 pa1 = *(const float4*)(xa + 4);
    float4 pa2 = *(const float4*)(xa + 8);
    float4 pa3 = *(const float4*)(xa + 12);
    float4 pb0 = *(const float4*)(wb + 0);
    float4 pb1 = *(const float4*)(wb + 4);

    float acc[8][8], accT[8][8];
#pragma unroll
    for (int i = 0; i < 8; ++i)
#pragma unroll
        for (int j = 0; j < 8; ++j) { acc[i][j] = 0.f; accT[i][j] = 0.f; }

    const int NTILE = KD / K1_BK;         // 128
    for (int ti = 0; ti < NTILE; ++ti) {
        const int buf = ti & 1;
        // ---- stage current tile (regs -> LDS); A k-major scalar (2-way banks)
        As[buf][ 0][t] = pa0.x; As[buf][ 1][t] = pa0.y;
        As[buf][ 2][t] = pa0.z; As[buf][ 3][t] = pa0.w;
        As[buf][ 4][t] = pa1.x; As[buf][ 5][t] = pa1.y;
        As[buf][ 6][t] = pa1.z; As[buf][ 7][t] = pa1.w;
        As[buf][ 8][t] = pa2.x; As[buf][ 9][t] = pa2.y;
        As[buf][10][t] = pa2.z; As[buf][11][t] = pa2.w;
        As[buf][12][t] = pa3.x; As[buf][13][t] = pa3.y;
        As[buf][14][t] = pa3.z; As[buf][15][t] = pa3.w;
        *(float4*)&Bs[buf][bkr][bnq]     = pb0;
        *(float4*)&Bs[buf][bkr][bnq + 4] = pb1;
        __syncthreads();                  // writes(buf) visible; buf^1 free
        // ---- prefetch next tile's global data (hidden under compute)
        if (ti + 1 < NTILE) {
            const float* xn = xa + (ti + 1) * K1_BK;
            const float* wn = wb + (size_t)(ti + 1) * K1_BK * PROJ;
            pa0 = *(const float4*)(xn + 0);
            pa1 = *(const float4*)(xn + 4);
            pa2 = *(const float4*)(xn + 8);
            pa3 = *(const float4*)(xn + 12);
            pb0 = *(const float4*)(wn + 0);
            pb1 = *(const float4*)(wn + 4);
        }
        // ---- compute: 16 kk x (4 b128 reads : 64 FMA)
#pragma unroll
        for (int kk = 0; kk < K1_BK; ++kk) {
            const float4 a0 = *(const float4*)&As[buf][kk][mg * 8];
            const float4 a1 = *(const float4*)&As[buf][kk][mg * 8 + 4];
            const float4 b0 = *(const float4*)&Bs[buf][kk][ng * 8];
            const float4 b1 = *(const float4*)&Bs[buf][kk][ng * 8 + 4];
            const float av[8] = { a0.x, a0.y, a0.z, a0.w, a1.x, a1.y, a1.z, a1.w };
            const float bv[8] = { b0.x, b0.y, b0.z, b0.w, b1.x, b1.y, b1.z, b1.w };
#pragma unroll
            for (int i = 0; i < 8; ++i)
#pragma unroll
                for (int j = 0; j < 8; ++j)
                    acc[i][j] = fmaf(av[i], bv[j], acc[i][j]);
        }
        if ((ti & 31) == 31) {            // fold every 512 k (rounding profile)
#pragma unroll
            for (int i = 0; i < 8; ++i)
#pragma unroll
                for (int j = 0; j < 8; ++j) { accT[i][j] += acc[i][j]; acc[i][j] = 0.f; }
        }
    }

    // ---- epilogue: bias + channel-major stores (2 x float4 per col)
    const float4 bp0 = *(const float4*)&bp[n0 + ng * 8];
    const float4 bp1 = *(const float4*)&bp[n0 + ng * 8 + 4];
    const float bb[8] = { bp0.x, bp0.y, bp0.z, bp0.w, bp1.x, bp1.y, bp1.z, bp1.w };
#pragma unroll
    for (int j = 0; j < 8; ++j) {
        float4 lo, hi;
        lo.x = accT[0][j] + bb[j]; lo.y = accT[1][j] + bb[j];
        lo.z = accT[2][j] + bb[j]; lo.w = accT[3][j] + bb[j];
        hi.x = accT[4][j] + bb[j]; hi.y = accT[5][j] + bb[j];
        hi.z = accT[6][j] + bb[j]; hi.w = accT[7][j] + bb[j];
        float* dst = &hT[(size_t)(n0 + ng * 8 + j) * NT + m0 + mg * 8];
        *(float4*)&dst[0] = lo;
        *(float4*)&dst[4] = hi;
    }
}

// ---------------------------------------------------------------------------
// K2: per head: hid = relu(h @ W1 + b1); hl = hid @ W2 + b2  (both 64x64 GEMMs)
// Channel-major h_T / hl_T. 256 thr, 128 tokens, one head. Per-thread
// 4e x 8tok; W1/W2 in LDS; hid tile through padded LDS; B-frags = global f4.
// ---------------------------------------------------------------------------
__global__ __launch_bounds__(256) void k2_heads(const float* __restrict__ hT,
                                                const float* __restrict__ W1,
                                                const float* __restrict__ b1,
                                                const float* __restrict__ W2,
                                                const float* __restrict__ b2,
                                                float* __restrict__ hlT)
{
    __shared__ float W1s[64][64];
    __shared__ float W2s[64][64];
    __shared__ float Hs[64][132];     // hid tile [d2][tok], pad 132

    const int t    = threadIdx.x;
    const int eg   = t & 15;          // e-group: e = eg*4 + j
    const int tg   = t >> 4;          // tok-group: tok = tok0 + tg*8 + i
    const int head = blockIdx.y;
    const int tok0 = blockIdx.x * 128;

    {   // stage weights (coalesced float4)
        const float4* g1 = (const float4*)(W1 + (size_t)head * HD * HD);
        const float4* g2 = (const float4*)(W2 + (size_t)head * HD * HD);
        float4* s1 = (float4*)&W1s[0][0];
        float4* s2 = (float4*)&W2s[0][0];
#pragma unroll
        for (int q = 0; q < 4; ++q) {
            s1[t + q * 256] = g1[t + q * 256];
            s2[t + q * 256] = g2[t + q * 256];
        }
    }
    const float4 b1v = *(const float4*)&b1[head * HD + eg * 4];
    const float4 b2v = *(const float4*)&b2[head * HD + eg * 4];
    __syncthreads();

    // ---- stage 1: hid[e][tok] = relu(b1 + sum_d h_T[head*64+d][tok]*W1[d][e])
    float acc[4][8];
    {
        const float bb[4] = { b1v.x, b1v.y, b1v.z, b1v.w };
#pragma unroll
        for (int j = 0; j < 4; ++j)
#pragma unroll
            for (int i = 0; i < 8; ++i) acc[j][i] = bb[j];
    }
    const float* hbase = &hT[(size_t)(head * HD) * NT + tok0 + tg * 8];
#pragma unroll 4
    for (int d = 0; d < HD; ++d) {
        const float4 w  = *(const float4*)&W1s[d][eg * 4];
        const float4 h0 = *(const float4*)&hbase[(size_t)d * NT];
        const float4 h1 = *(const float4*)&hbase[(size_t)d * NT + 4];
        const float wv[4] = { w.x, w.y, w.z, w.w };
        const float hv[8] = { h0.x, h0.y, h0.z, h0.w, h1.x, h1.y, h1.z, h1.w };
#pragma unroll
        for (int j = 0; j < 4; ++j)
#pragma unroll
            for (int i = 0; i < 8; ++i)
                acc[j][i] = fmaf(wv[j], hv[i], acc[j][i]);
    }
#pragma unroll
    for (int j = 0; j < 4; ++j) {
        float4 lo, hi;
        lo.x = fmaxf(acc[j][0], 0.f); lo.y = fmaxf(acc[j][1], 0.f);
        lo.z = fmaxf(acc[j][2], 0.f); lo.w = fmaxf(acc[j][3], 0.f);
        hi.x = fmaxf(acc[j][4], 0.f); hi.y = fmaxf(acc[j][5], 0.f);
        hi.z = fmaxf(acc[j][6], 0.f); hi.w = fmaxf(acc[j][7], 0.f);
        *(float4*)&Hs[eg * 4 + j][tg * 8]     = lo;
        *(float4*)&Hs[eg * 4 + j][tg * 8 + 4] = hi;
    }
    __syncthreads();

    // ---- stage 2: hl[e][tok] = b2 + sum_d2 Hs[d2][tok]*W2[d2][e]
    {
        const float bb[4] = { b2v.x, b2v.y, b2v.z, b2v.w };
#pragma unroll
        for (int j = 0; j < 4; ++j)
#pragma unroll
            for (int i = 0; i < 8; ++i) acc[j][i] = bb[j];
    }
#pragma unroll 4
    for (int d = 0; d < HD; ++d) {
        const float4 w  = *(const float4*)&W2s[d][eg * 4];
        const float4 h0 = *(const float4*)&Hs[d][tg * 8];
        const float4 h1 = *(const float4*)&Hs[d][tg * 8 + 4];
        const float wv[4] = { w.x, w.y, w.z, w.w };
        const float hv[8] = { h0.x, h0.y, h0.z, h0.w, h1.x, h1.y, h1.z, h1.w };
#pragma unroll
        for (int j = 0; j < 4; ++j)
#pragma unroll
            for (int i = 0; i < 8; ++i)
                acc[j][i] = fmaf(wv[j], hv[i], acc[j][i]);
    }
#pragma unroll
    for (int j = 0; j < 4; ++j) {
        float4 lo = { acc[j][0], acc[j][1], acc[j][2], acc[j][3] };
        float4 hi = { acc[j][4], acc[j][5], acc[j][6], acc[j][7] };
        float* dst = &hlT[(size_t)(head * HD + eg * 4 + j) * NT + tok0 + tg * 8];
        *(float4*)&dst[0] = lo;
        *(float4*)&dst[4] = hi;
    }
}

// ---------------------------------------------------------------------------
// K3: gl[tok][e] = (hl_T[:, tok] . Wc[:, e] + bc[e]) / clip(T); top-2 softmax.
// 512 thr, 64 tokens/block, per-thread 4e x 2tok. No LDS; Wc L1/L2-resident.
// ---------------------------------------------------------------------------
__global__ __launch_bounds__(512) void k3_gate(const float* __restrict__ hlT,
                                               const float* __restrict__ Wc,
                                               const float* __restrict__ bc,
                                               const float* __restrict__ temp,
                                               float* __restrict__ out)
{
    const int t    = threadIdx.x;
    const int eg   = t & 15;          // e = eg*4 + j  (low lane bits -> shfl ok)
    const int tg   = t >> 4;          // 0..31: tok = tok0 + tg*2 + i
    const int tok0 = blockIdx.x * 64;

    const float tv  = fminf(fmaxf(temp[0], 0.5f), 5.0f);
    const float inv = 1.0f / tv;      // uniform scale: ordering identical to /tv
    const float4 bcv = *(const float4*)&bc[eg * 4];

    float acc[4][2];
    acc[0][0] = bcv.x; acc[0][1] = bcv.x;
    acc[1][0] = bcv.y; acc[1][1] = bcv.y;
    acc[2][0] = bcv.z; acc[2][1] = bcv.z;
    acc[3][0] = bcv.w; acc[3][1] = bcv.w;

    const float* hb = &hlT[tok0 + tg * 2];
#pragma unroll 8
    for (int k = 0; k < PROJ; ++k) {
        const float2 hv = *(const float2*)&hb[(size_t)k * NT];
        const float4 wv = *(const float4*)&Wc[k * NE + eg * 4];
        const float wa[4] = { wv.x, wv.y, wv.z, wv.w };
#pragma unroll
        for (int j = 0; j < 4; ++j) {
            acc[j][0] = fmaf(wa[j], hv.x, acc[j][0]);
            acc[j][1] = fmaf(wa[j], hv.y, acc[j][1]);
        }
    }

#pragma unroll
    for (int i = 0; i < 2; ++i) {
        const int tok = tok0 + tg * 2 + i;
        float gl_[4];
#pragma unroll
        for (int j = 0; j < 4; ++j) gl_[j] = acc[j][i] * inv;

        // top-1 (strict > keeps lowest index; cross-lane ties -> lower index)
        float v1 = gl_[0]; int i1 = eg * 4;
#pragma unroll
        for (int j = 1; j < 4; ++j)
            if (gl_[j] > v1) { v1 = gl_[j]; i1 = eg * 4 + j; }
#pragma unroll
        for (int off = 8; off >= 1; off >>= 1) {
            const float ov = __shfl_xor(v1, off);
            const int   oi = __shfl_xor(i1, off);
            if (ov > v1 || (ov == v1 && oi < i1)) { v1 = ov; i1 = oi; }
        }
        // top-2: exclude winner
        float v2 = -INFINITY; int i2 = NE;
#pragma unroll
        for (int j = 0; j < 4; ++j) {
            const int e = eg * 4 + j;
            if (e != i1 && gl_[j] > v2) { v2 = gl_[j]; i2 = e; }
        }
#pragma unroll
        for (int off = 8; off >= 1; off >>= 1) {
            const float ov = __shfl_xor(v2, off);
            const int   oi = __shfl_xor(i2, off);
            if (ov > v2 || (ov == v2 && oi < i2)) { v2 = ov; i2 = oi; }
        }

        const float e2  = expf(v2 - v1);
        const float s   = 1.f + e2;
        const float g1v = 1.f / s;
        const float g2v = e2 / s;

        float4 gv;
        {
            const int e0 = eg * 4;
            gv.x = (e0 + 0 == i1) ? g1v : ((e0 + 0 == i2) ? g2v : 0.f);
            gv.y = (e0 + 1 == i1) ? g1v : ((e0 + 1 == i2) ? g2v : 0.f);
            gv.z = (e0 + 2 == i1) ? g1v : ((e0 + 2 == i2) ? g2v : 0.f);
            gv.w = (e0 + 3 == i1) ? g1v : ((e0 + 3 == i2) ? g2v : 0.f);
        }
        *(float4*)&out[GATES_OFF + (size_t)tok * NE + eg * 4] = gv;
        const float4 glv = { gl_[0], gl_[1], gl_[2], gl_[3] };
        *(float4*)&out[GL_OFF + (size_t)tok * NE + eg * 4] = glv;
        if (eg == 0) {
            out[IDX_OFF + (size_t)tok * 2 + 0] = (float)i1;
            out[IDX_OFF + (size_t)tok * 2 + 1] = (float)i2;
        }
    }
}

// ---------------------------------------------------------------------------
extern "C" void kernel_launch(void* const* d_in, const int* in_sizes, int n_in,
                              void* d_out, int out_size, void* d_ws, size_t ws_size,
                              hipStream_t stream)
{
    (void)in_sizes; (void)n_in; (void)out_size; (void)ws_size;

    const float* x    = (const float*)d_in[0];
    const float* Wp   = (const float*)d_in[1];
    const float* bp   = (const float*)d_in[2];
    const float* W1   = (const float*)d_in[3];
    const float* b1   = (const float*)d_in[4];
    const float* W2   = (const float*)d_in[5];
    const float* b2   = (const float*)d_in[6];
    const float* Wc   = (const float*)d_in[7];
    const float* bc   = (const float*)d_in[8];
    const float* temp = (const float*)d_in[9];

    float* out = (float*)d_out;
    float* hT  = (float*)d_ws;                    // [256][16384] f32, 16.8 MB
    float* hlT = hT + (size_t)PROJ * NT;          // [256][16384] f32, 16.8 MB

    k1_gemm <<<dim3(NT / 128, PROJ / 64), 128, 0, stream>>>(x, Wp, bp, hT);
    k2_heads<<<dim3(NT / 128, NH),        256, 0, stream>>>(hT, W1, b1, W2, b2, hlT);
    k3_gate <<<dim3(NT / 64),             512, 0, stream>>>(hlT, Wc, bc, temp, out);
}

// Round 7
// 231.964 us; speedup vs baseline: 1.5589x; 1.3821x over previous
//
#include <hip/hip_runtime.h>
#include <math.h>

#define NT   16384
#define KD   2048
#define PROJ 256
#define NH   4
#define HD   64
#define NE   64

#define GATES_OFF 0
#define IDX_OFF   (NT * NE)            // 1048576
#define GL_OFF    (NT * NE + NT * 2)   // 1081344

typedef __attribute__((ext_vector_type(8))) short short8;   // 8 bf16 (4 VGPR)
typedef __attribute__((ext_vector_type(4))) float f32x4;    // MFMA C/D

static __device__ __forceinline__ ushort f2bf_rne(float f) {
    uint u = __float_as_uint(f);
    u += 0x7FFFu + ((u >> 16) & 1u);     // round-to-nearest-even
    return (ushort)(u >> 16);
}
static __device__ __forceinline__ float bf2f(ushort b) {
    return __uint_as_float(((uint)b) << 16);
}

// ---------------------------------------------------------------------------
// K0: split Wp[k][c] (f32) into transposed bf16 hi/lo: WpT_*[c][k].
// hi = RNE(bf16(v)); lo = RNE(bf16(v - hi)).  524288 elems, trivial cost.
// ---------------------------------------------------------------------------
__global__ __launch_bounds__(256) void k0_split(const float* __restrict__ Wp,
                                                ushort* __restrict__ WpT_hi,
                                                ushort* __restrict__ WpT_lo)
{
    const int tid = blockIdx.x * 256 + threadIdx.x;   // 131072 threads
#pragma unroll
    for (int e = 0; e < 4; ++e) {
        const int idx = tid + e * 131072;             // coalesced read
        const int k = idx >> 8, c = idx & 255;
        const float v = Wp[idx];
        const ushort hi = f2bf_rne(v);
        const ushort lo = f2bf_rne(v - bf2f(hi));
        WpT_hi[(size_t)c * KD + k] = hi;
        WpT_lo[(size_t)c * KD + k] = lo;
    }
}

// ---------------------------------------------------------------------------
// K1: h_T[c][tok] = x @ Wp + bp via bf16 split-3 MFMA (error ~2^-17 rel).
// Tile 128m x 128n, BK=32, 256 thr = 4 waves (2x2), wave-tile 64x64
// (16 frags, 48 MFMA : 16 ds_read_b128 per k-tile). LDS holds A and B in
// FRAGMENT order (lane-contiguous 16B -> conflict-free reads). A is split
// on the fly from f32 x; B comes pre-split from WpT_hi/lo. One barrier per
// k-tile, register prefetch (proven R3/R6 skeleton). C/D layout per m89:
// col = lane&15, row = (lane>>4)*4 + reg -> float4 store per frag.
// ---------------------------------------------------------------------------
__global__ __launch_bounds__(256) void k1_mfma(const float* __restrict__ x,
                                               const ushort* __restrict__ WpT_hi,
                                               const ushort* __restrict__ WpT_lo,
                                               const float* __restrict__ bp,
                                               float* __restrict__ hT)
{
    // A frags: [gm 0..7][lane 0..63][8 bf16]   (8 KB each)
    __shared__ ushort Ah[2][4096], Al[2][4096];
    // B rows:  [c 0..127][40 bf16 padded]      (10 KB each; pad -> <=2-way)
    __shared__ ushort Bh[2][5120], Bl[2][5120];

    const int t   = threadIdx.x;
    const int wid = t >> 6;
    const int wm  = wid >> 1;          // wave m: 0..1
    const int wn  = wid & 1;           // wave n: 0..1
    const int l   = t & 63;
    const int m0  = blockIdx.x * 128;
    const int n0  = blockIdx.y * 128;

    f32x4 acc[4][4];
#pragma unroll
    for (int m = 0; m < 4; ++m)
#pragma unroll
        for (int n = 0; n < 4; ++n) acc[m][n] = (f32x4){0.f, 0.f, 0.f, 0.f};

    // ---- prefetch tile 0
    float4 pa[4];
    uint4  pbh[2], pbl[2];
#pragma unroll
    for (int it = 0; it < 4; ++it) {
        const int fidx = t + it * 256;
        const int arow = fidx >> 3, kq = fidx & 7;
        pa[it] = *(const float4*)&x[(size_t)(m0 + arow) * KD + kq * 4];
    }
#pragma unroll
    for (int it = 0; it < 2; ++it) {
        const int cidx = t + it * 256;
        const int brow = cidx >> 2, q = cidx & 3;
        pbh[it] = *(const uint4*)&WpT_hi[(size_t)(n0 + brow) * KD + q * 8];
        pbl[it] = *(const uint4*)&WpT_lo[(size_t)(n0 + brow) * KD + q * 8];
    }

    const int NTILE = KD / 32;   // 64
    for (int ti = 0; ti < NTILE; ++ti) {
        const int buf = ti & 1;
        // ---- stage A (convert f32 -> bf16 hi/lo, fragment-ordered)
#pragma unroll
        for (int it = 0; it < 4; ++it) {
            const int fidx = t + it * 256;
            const int arow = fidx >> 3, kq = fidx & 7;
            const float vv[4] = { pa[it].x, pa[it].y, pa[it].z, pa[it].w };
            ushort hi[4], lo[4];
#pragma unroll
            for (int e = 0; e < 4; ++e) {
                hi[e] = f2bf_rne(vv[e]);
                lo[e] = f2bf_rne(vv[e] - bf2f(hi[e]));
            }
            const int off = ((arow >> 4) * 64 + (arow & 15) + ((kq >> 1) << 4)) * 8
                          + (kq & 1) * 4;
            uint2 wh = { (uint)hi[0] | ((uint)hi[1] << 16),
                         (uint)hi[2] | ((uint)hi[3] << 16) };
            uint2 wl = { (uint)lo[0] | ((uint)lo[1] << 16),
                         (uint)lo[2] | ((uint)lo[3] << 16) };
            *(uint2*)&Ah[buf][off] = wh;
            *(uint2*)&Al[buf][off] = wl;
        }
        // ---- stage B (already bf16, row-contiguous)
#pragma unroll
        for (int it = 0; it < 2; ++it) {
            const int cidx = t + it * 256;
            const int brow = cidx >> 2, q = cidx & 3;
            *(uint4*)&Bh[buf][brow * 40 + q * 8] = pbh[it];
            *(uint4*)&Bl[buf][brow * 40 + q * 8] = pbl[it];
        }
        __syncthreads();
        // ---- prefetch next tile (overlaps MFMA below)
        if (ti + 1 < NTILE) {
            const int kb = (ti + 1) * 32;
#pragma unroll
            for (int it = 0; it < 4; ++it) {
                const int fidx = t + it * 256;
                const int arow = fidx >> 3, kq = fidx & 7;
                pa[it] = *(const float4*)&x[(size_t)(m0 + arow) * KD + kb + kq * 4];
            }
#pragma unroll
            for (int it = 0; it < 2; ++it) {
                const int cidx = t + it * 256;
                const int brow = cidx >> 2, q = cidx & 3;
                pbh[it] = *(const uint4*)&WpT_hi[(size_t)(n0 + brow) * KD + kb + q * 8];
                pbl[it] = *(const uint4*)&WpT_lo[(size_t)(n0 + brow) * KD + kb + q * 8];
            }
        }
        // ---- load fragments (conflict-free b128)
        short8 ah[4], al[4], bh[4], bl[4];
#pragma unroll
        for (int m = 0; m < 4; ++m) {
            const int off = ((wm * 4 + m) * 64 + l) * 8;
            ah[m] = *(const short8*)&Ah[buf][off];
            al[m] = *(const short8*)&Al[buf][off];
        }
#pragma unroll
        for (int n = 0; n < 4; ++n) {
            const int row = wn * 64 + n * 16 + (l & 15);
            const int off = row * 40 + (l >> 4) * 8;
            bh[n] = *(const short8*)&Bh[buf][off];
            bl[n] = *(const short8*)&Bl[buf][off];
        }
        // ---- 48 MFMA: hi*hi + hi*lo + lo*hi into f32 acc
#pragma unroll
        for (int m = 0; m < 4; ++m)
#pragma unroll
            for (int n = 0; n < 4; ++n) {
                acc[m][n] = __builtin_amdgcn_mfma_f32_16x16x32_bf16(ah[m], bh[n], acc[m][n], 0, 0, 0);
                acc[m][n] = __builtin_amdgcn_mfma_f32_16x16x32_bf16(ah[m], bl[n], acc[m][n], 0, 0, 0);
                acc[m][n] = __builtin_amdgcn_mfma_f32_16x16x32_bf16(al[m], bh[n], acc[m][n], 0, 0, 0);
            }
        __syncthreads();   // all reads of buf done before it is overwritten
    }

    // ---- epilogue: bias + channel-major float4 stores
#pragma unroll
    for (int n = 0; n < 4; ++n) {
        const int col = n0 + wn * 64 + n * 16 + (l & 15);
        const float b = bp[col];
#pragma unroll
        for (int m = 0; m < 4; ++m) {
            const int tok = m0 + wm * 64 + m * 16 + (l >> 4) * 4;
            float4 st = { acc[m][n].x + b, acc[m][n].y + b,
                          acc[m][n].z + b, acc[m][n].w + b };
            *(float4*)&hT[(size_t)col * NT + tok] = st;
        }
    }
}

// ---------------------------------------------------------------------------
// K2: per head: hid = relu(h @ W1 + b1); hl = hid @ W2 + b2  (both 64x64 GEMMs)
// Channel-major h_T / hl_T. 256 thr, 128 tokens, one head. Per-thread
// 4e x 8tok; W1/W2 in LDS; hid tile through padded LDS; B-frags = global f4.
// ---------------------------------------------------------------------------
__global__ __launch_bounds__(256) void k2_heads(const float* __restrict__ hT,
                                                const float* __restrict__ W1,
                                                const float* __restrict__ b1,
                                                const float* __restrict__ W2,
                                                const float* __restrict__ b2,
                                                float* __restrict__ hlT)
{
    __shared__ float W1s[64][64];
    __shared__ float W2s[64][64];
    __shared__ float Hs[64][132];     // hid tile [d2][tok], pad 132

    const int t    = threadIdx.x;
    const int eg   = t & 15;          // e-group: e = eg*4 + j
    const int tg   = t >> 4;          // tok-group: tok = tok0 + tg*8 + i
    const int head = blockIdx.y;
    const int tok0 = blockIdx.x * 128;

    {   // stage weights (coalesced float4)
        const float4* g1 = (const float4*)(W1 + (size_t)head * HD * HD);
        const float4* g2 = (const float4*)(W2 + (size_t)head * HD * HD);
        float4* s1 = (float4*)&W1s[0][0];
        float4* s2 = (float4*)&W2s[0][0];
#pragma unroll
        for (int q = 0; q < 4; ++q) {
            s1[t + q * 256] = g1[t + q * 256];
            s2[t + q * 256] = g2[t + q * 256];
        }
    }
    const float4 b1v = *(const float4*)&b1[head * HD + eg * 4];
    const float4 b2v = *(const float4*)&b2[head * HD + eg * 4];
    __syncthreads();

    // ---- stage 1: hid[e][tok] = relu(b1 + sum_d h_T[head*64+d][tok]*W1[d][e])
    float acc[4][8];
    {
        const float bb[4] = { b1v.x, b1v.y, b1v.z, b1v.w };
#pragma unroll
        for (int j = 0; j < 4; ++j)
#pragma unroll
            for (int i = 0; i < 8; ++i) acc[j][i] = bb[j];
    }
    const float* hbase = &hT[(size_t)(head * HD) * NT + tok0 + tg * 8];
#pragma unroll 4
    for (int d = 0; d < HD; ++d) {
        const float4 w  = *(const float4*)&W1s[d][eg * 4];
        const float4 h0 = *(const float4*)&hbase[(size_t)d * NT];
        const float4 h1 = *(const float4*)&hbase[(size_t)d * NT + 4];
        const float wv[4] = { w.x, w.y, w.z, w.w };
        const float hv[8] = { h0.x, h0.y, h0.z, h0.w, h1.x, h1.y, h1.z, h1.w };
#pragma unroll
        for (int j = 0; j < 4; ++j)
#pragma unroll
            for (int i = 0; i < 8; ++i)
                acc[j][i] = fmaf(wv[j], hv[i], acc[j][i]);
    }
#pragma unroll
    for (int j = 0; j < 4; ++j) {
        float4 lo, hi;
        lo.x = fmaxf(acc[j][0], 0.f); lo.y = fmaxf(acc[j][1], 0.f);
        lo.z = fmaxf(acc[j][2], 0.f); lo.w = fmaxf(acc[j][3], 0.f);
        hi.x = fmaxf(acc[j][4], 0.f); hi.y = fmaxf(acc[j][5], 0.f);
        hi.z = fmaxf(acc[j][6], 0.f); hi.w = fmaxf(acc[j][7], 0.f);
        *(float4*)&Hs[eg * 4 + j][tg * 8]     = lo;
        *(float4*)&Hs[eg * 4 + j][tg * 8 + 4] = hi;
    }
    __syncthreads();

    // ---- stage 2: hl[e][tok] = b2 + sum_d2 Hs[d2][tok]*W2[d2][e]
    {
        const float bb[4] = { b2v.x, b2v.y, b2v.z, b2v.w };
#pragma unroll
        for (int j = 0; j < 4; ++j)
#pragma unroll
            for (int i = 0; i < 8; ++i) acc[j][i] = bb[j];
    }
#pragma unroll 4
    for (int d = 0; d < HD; ++d) {
        const float4 w  = *(const float4*)&W2s[d][eg * 4];
        const float4 h0 = *(const float4*)&Hs[d][tg * 8];
        const float4 h1 = *(const float4*)&Hs[d][tg * 8 + 4];
        const float wv[4] = { w.x, w.y, w.z, w.w };
        const float hv[8] = { h0.x, h0.y, h0.z, h0.w, h1.x, h1.y, h1.z, h1.w };
#pragma unroll
        for (int j = 0; j < 4; ++j)
#pragma unroll
            for (int i = 0; i < 8; ++i)
                acc[j][i] = fmaf(wv[j], hv[i], acc[j][i]);
    }
#pragma unroll
    for (int j = 0; j < 4; ++j) {
        float4 lo = { acc[j][0], acc[j][1], acc[j][2], acc[j][3] };
        float4 hi = { acc[j][4], acc[j][5], acc[j][6], acc[j][7] };
        float* dst = &hlT[(size_t)(head * HD + eg * 4 + j) * NT + tok0 + tg * 8];
        *(float4*)&dst[0] = lo;
        *(float4*)&dst[4] = hi;
    }
}

// ---------------------------------------------------------------------------
// K3: gl[tok][e] = (hl_T[:, tok] . Wc[:, e] + bc[e]) / clip(T); top-2 softmax.
// 512 thr, 64 tokens/block, per-thread 4e x 2tok. No LDS; Wc L1/L2-resident.
// ---------------------------------------------------------------------------
__global__ __launch_bounds__(512) void k3_gate(const float* __restrict__ hlT,
                                               const float* __restrict__ Wc,
                                               const float* __restrict__ bc,
                                               const float* __restrict__ temp,
                                               float* __restrict__ out)
{
    const int t    = threadIdx.x;
    const int eg   = t & 15;          // e = eg*4 + j  (low lane bits -> shfl ok)
    const int tg   = t >> 4;          // 0..31: tok = tok0 + tg*2 + i
    const int tok0 = blockIdx.x * 64;

    const float tv  = fminf(fmaxf(temp[0], 0.5f), 5.0f);
    const float inv = 1.0f / tv;      // uniform scale: ordering identical to /tv
    const float4 bcv = *(const float4*)&bc[eg * 4];

    float acc[4][2];
    acc[0][0] = bcv.x; acc[0][1] = bcv.x;
    acc[1][0] = bcv.y; acc[1][1] = bcv.y;
    acc[2][0] = bcv.z; acc[2][1] = bcv.z;
    acc[3][0] = bcv.w; acc[3][1] = bcv.w;

    const float* hb = &hlT[tok0 + tg * 2];
#pragma unroll 8
    for (int k = 0; k < PROJ; ++k) {
        const float2 hv = *(const float2*)&hb[(size_t)k * NT];
        const float4 wv = *(const float4*)&Wc[k * NE + eg * 4];
        const float wa[4] = { wv.x, wv.y, wv.z, wv.w };
#pragma unroll
        for (int j = 0; j < 4; ++j) {
            acc[j][0] = fmaf(wa[j], hv.x, acc[j][0]);
            acc[j][1] = fmaf(wa[j], hv.y, acc[j][1]);
        }
    }

#pragma unroll
    for (int i = 0; i < 2; ++i) {
        const int tok = tok0 + tg * 2 + i;
        float gl_[4];
#pragma unroll
        for (int j = 0; j < 4; ++j) gl_[j] = acc[j][i] * inv;

        // top-1 (strict > keeps lowest index; cross-lane ties -> lower index)
        float v1 = gl_[0]; int i1 = eg * 4;
#pragma unroll
        for (int j = 1; j < 4; ++j)
            if (gl_[j] > v1) { v1 = gl_[j]; i1 = eg * 4 + j; }
#pragma unroll
        for (int off = 8; off >= 1; off >>= 1) {
            const float ov = __shfl_xor(v1, off);
            const int   oi = __shfl_xor(i1, off);
            if (ov > v1 || (ov == v1 && oi < i1)) { v1 = ov; i1 = oi; }
        }
        // top-2: exclude winner
        float v2 = -INFINITY; int i2 = NE;
#pragma unroll
        for (int j = 0; j < 4; ++j) {
            const int e = eg * 4 + j;
            if (e != i1 && gl_[j] > v2) { v2 = gl_[j]; i2 = e; }
        }
#pragma unroll
        for (int off = 8; off >= 1; off >>= 1) {
            const float ov = __shfl_xor(v2, off);
            const int   oi = __shfl_xor(i2, off);
            if (ov > v2 || (ov == v2 && oi < i2)) { v2 = ov; i2 = oi; }
        }

        const float e2  = expf(v2 - v1);
        const float s   = 1.f + e2;
        const float g1v = 1.f / s;
        const float g2v = e2 / s;

        float4 gv;
        {
            const int e0 = eg * 4;
            gv.x = (e0 + 0 == i1) ? g1v : ((e0 + 0 == i2) ? g2v : 0.f);
            gv.y = (e0 + 1 == i1) ? g1v : ((e0 + 1 == i2) ? g2v : 0.f);
            gv.z = (e0 + 2 == i1) ? g1v : ((e0 + 2 == i2) ? g2v : 0.f);
            gv.w = (e0 + 3 == i1) ? g1v : ((e0 + 3 == i2) ? g2v : 0.f);
        }
        *(float4*)&out[GATES_OFF + (size_t)tok * NE + eg * 4] = gv;
        const float4 glv = { gl_[0], gl_[1], gl_[2], gl_[3] };
        *(float4*)&out[GL_OFF + (size_t)tok * NE + eg * 4] = glv;
        if (eg == 0) {
            out[IDX_OFF + (size_t)tok * 2 + 0] = (float)i1;
            out[IDX_OFF + (size_t)tok * 2 + 1] = (float)i2;
        }
    }
}

// ---------------------------------------------------------------------------
extern "C" void kernel_launch(void* const* d_in, const int* in_sizes, int n_in,
                              void* d_out, int out_size, void* d_ws, size_t ws_size,
                              hipStream_t stream)
{
    (void)in_sizes; (void)n_in; (void)out_size; (void)ws_size;

    const float* x    = (const float*)d_in[0];
    const float* Wp   = (const float*)d_in[1];
    const float* bp   = (const float*)d_in[2];
    const float* W1   = (const float*)d_in[3];
    const float* b1   = (const float*)d_in[4];
    const float* W2   = (const float*)d_in[5];
    const float* b2   = (const float*)d_in[6];
    const float* Wc   = (const float*)d_in[7];
    const float* bc   = (const float*)d_in[8];
    const float* temp = (const float*)d_in[9];

    float* out = (float*)d_out;
    float* hT  = (float*)d_ws;                    // [256][16384] f32, 16.8 MB
    float* hlT = hT + (size_t)PROJ * NT;          // [256][16384] f32, 16.8 MB

    // Wp bf16 hi/lo splits live in the hlT region (dead until k2 writes it).
    ushort* WpT_hi = (ushort*)hlT;                // 1 MB
    ushort* WpT_lo = WpT_hi + (size_t)KD * PROJ;  // 1 MB

    k0_split<<<dim3(512),            256, 0, stream>>>(Wp, WpT_hi, WpT_lo);
    k1_mfma <<<dim3(NT / 128, 2),    256, 0, stream>>>(x, WpT_hi, WpT_lo, bp, hT);
    k2_heads<<<dim3(NT / 128, NH),   256, 0, stream>>>(hT, W1, b1, W2, b2, hlT);
    k3_gate <<<dim3(NT / 64),        512, 0, stream>>>(hlT, Wc, bc, temp, out);
}

// Round 8
// 229.730 us; speedup vs baseline: 1.5740x; 1.0097x over previous
//
#include <hip/hip_runtime.h>
#include <math.h>

#define NT   16384
#define KD   2048
#define PROJ 256
#define NH   4
#define HD   64
#define NE   64

#define GATES_OFF 0
#define IDX_OFF   (NT * NE)            // 1048576
#define GL_OFF    (NT * NE + NT * 2)   // 1081344

typedef __attribute__((ext_vector_type(8))) short short8;   // 8 bf16 (4 VGPR)
typedef __attribute__((ext_vector_type(4))) float f32x4;    // MFMA C/D

static __device__ __forceinline__ ushort f2bf_rne(float f) {
    uint u = __float_as_uint(f);
    u += 0x7FFFu + ((u >> 16) & 1u);
    return (ushort)(u >> 16);
}
static __device__ __forceinline__ float bf2f(ushort b) {
    return __uint_as_float(((uint)b) << 16);
}

// ---------------------------------------------------------------------------
// K0: split Wp[k][c] (f32) into transposed bf16 hi/lo: WpT_*[c][k]. RNE split.
// ---------------------------------------------------------------------------
__global__ __launch_bounds__(256) void k0_split(const float* __restrict__ Wp,
                                                ushort* __restrict__ WpT_hi,
                                                ushort* __restrict__ WpT_lo)
{
    const int tid = blockIdx.x * 256 + threadIdx.x;   // 131072 threads
#pragma unroll
    for (int e = 0; e < 4; ++e) {
        const int idx = tid + e * 131072;             // coalesced read
        const int k = idx >> 8, c = idx & 255;
        const float v = Wp[idx];
        const ushort hi = f2bf_rne(v);
        const ushort lo = f2bf_rne(v - bf2f(hi));
        WpT_hi[(size_t)c * KD + k] = hi;
        WpT_lo[(size_t)c * KD + k] = lo;
    }
}

// ---------------------------------------------------------------------------
// K1: h_T = x @ Wp + bp via bf16 split-3 MFMA.
// 128m x 128n tile, BK=32, 256 thr = 4 waves (2x2), wave-tile 64x64.
// A: f32 x loaded to regs, truncation-split to bf16 hi/lo, staged in LDS in
//    lane-contiguous fragment order (conflict-free b128 write+read), shared
//    by the 2 wn-waves. Double-buffered, ONE barrier per k-tile.
// B: pre-split WpT hi/lo (2 MB, L2-resident) fragment-loaded DIRECTLY from
//    global into registers, ping-ponged across the 2x-unrolled tile loop.
// 48 MFMA : 8 LDS reads per wave per tile.
// ---------------------------------------------------------------------------
__global__ __launch_bounds__(256) void k1_mfma(const float* __restrict__ x,
                                               const ushort* __restrict__ WpT_hi,
                                               const ushort* __restrict__ WpT_lo,
                                               const float* __restrict__ bp,
                                               float* __restrict__ hT)
{
    __shared__ ushort Ah[2][4096], Al[2][4096];   // 8 KB each bank; 32 KB total

    const int t   = threadIdx.x;
    const int wid = t >> 6;
    const int wm4 = (wid >> 1) * 4;    // wave m-frag base: 0 or 4
    const int wn  = wid & 1;
    const int l   = t & 63;
    const int m0  = blockIdx.x * 128;
    const int n0  = blockIdx.y * 128;

    // A staging slots: thread t handles slots t and t+256.
    // slot s: frag f = s>>6, lane ll = s&63 -> row m0+16f+(s&15), k (s>>4)&3 *8
    const int s0 = t, s1 = t + 256;
    const float* xa0 = &x[(size_t)(m0 + 16 * (s0 >> 6) + (s0 & 15)) * KD + ((s0 >> 4) & 3) * 8];
    const float* xa1 = &x[(size_t)(m0 + 16 * (s1 >> 6) + (s1 & 15)) * KD + ((s1 >> 4) & 3) * 8];

    // B fragment base: frag n -> col n0 + wn*64 + n*16 + (l&15), k (l>>4)*8
    const ushort* wph = &WpT_hi[(size_t)(n0 + wn * 64 + (l & 15)) * KD + (l >> 4) * 8];
    const ushort* wpl = &WpT_lo[(size_t)(n0 + wn * 64 + (l & 15)) * KD + (l >> 4) * 8];

    f32x4 acc[4][4];
#pragma unroll
    for (int m = 0; m < 4; ++m)
#pragma unroll
        for (int n = 0; n < 4; ++n) acc[m][n] = (f32x4){0.f, 0.f, 0.f, 0.f};

#define K1_STAGE_SLOT(DH, DL, VA, VB)                                          \
    {                                                                          \
        const float ff[8] = { (VA).x, (VA).y, (VA).z, (VA).w,                  \
                              (VB).x, (VB).y, (VB).z, (VB).w };                \
        uint hp[4], lp[4];                                                     \
        _Pragma("unroll")                                                      \
        for (int i = 0; i < 4; ++i) {                                          \
            const uint u0 = __float_as_uint(ff[2 * i]);                        \
            const uint u1 = __float_as_uint(ff[2 * i + 1]);                    \
            hp[i] = (u0 >> 16) | (u1 & 0xFFFF0000u);                           \
            const float r0 = ff[2 * i]     - __uint_as_float(u0 & 0xFFFF0000u);\
            const float r1 = ff[2 * i + 1] - __uint_as_float(u1 & 0xFFFF0000u);\
            lp[i] = (__float_as_uint(r0) >> 16) |                              \
                    (__float_as_uint(r1) & 0xFFFF0000u);                       \
        }                                                                      \
        *(uint4*)(DH) = (uint4){hp[0], hp[1], hp[2], hp[3]};                   \
        *(uint4*)(DL) = (uint4){lp[0], lp[1], lp[2], lp[3]};                   \
    }

#define K1_STAGE(BUF, R0, R1, R2, R3)                                          \
    K1_STAGE_SLOT(&Ah[BUF][s0 * 8], &Al[BUF][s0 * 8], R0, R1);                 \
    K1_STAGE_SLOT(&Ah[BUF][s1 * 8], &Al[BUF][s1 * 8], R2, R3);

#define K1_LOADA(KB, R0, R1, R2, R3)                                           \
    R0 = *(const float4*)(xa0 + (KB));                                         \
    R1 = *(const float4*)(xa0 + (KB) + 4);                                     \
    R2 = *(const float4*)(xa1 + (KB));                                         \
    R3 = *(const float4*)(xa1 + (KB) + 4);

#define K1_LOADB(KB, BH, BL)                                                   \
    _Pragma("unroll")                                                          \
    for (int n = 0; n < 4; ++n) {                                              \
        BH[n] = *(const short8*)(wph + (size_t)n * 16 * KD + (KB));            \
        BL[n] = *(const short8*)(wpl + (size_t)n * 16 * KD + (KB));            \
    }

#define K1_MFMA(BUF, BH, BL)                                                   \
    _Pragma("unroll")                                                          \
    for (int m = 0; m < 4; ++m) {                                              \
        const short8 ah = *(const short8*)&Ah[BUF][((wm4 + m) * 64 + l) * 8];  \
        const short8 al = *(const short8*)&Al[BUF][((wm4 + m) * 64 + l) * 8];  \
        _Pragma("unroll")                                                      \
        for (int n = 0; n < 4; ++n) {                                          \
            acc[m][n] = __builtin_amdgcn_mfma_f32_16x16x32_bf16(ah, BH[n], acc[m][n], 0, 0, 0); \
            acc[m][n] = __builtin_amdgcn_mfma_f32_16x16x32_bf16(ah, BL[n], acc[m][n], 0, 0, 0); \
            acc[m][n] = __builtin_amdgcn_mfma_f32_16x16x32_bf16(al, BH[n], acc[m][n], 0, 0, 0); \
        }                                                                      \
    }

    float4 xA0, xA1, xA2, xA3, xB0, xB1, xB2, xB3;
    short8 bhA[4], blA[4], bhB[4], blB[4];

    K1_LOADA(0, xA0, xA1, xA2, xA3);
    K1_LOADB(0, bhA, blA);

    for (int tp = 0; tp < 32; ++tp) {           // 2 k-tiles per iteration
        const int kb1 = (2 * tp + 1) * 32;
        const int kb2 = (2 * tp + 2) * 32;
        // ---- tile 2tp (buf 0, cur=A-set, next=B-set)
        K1_STAGE(0, xA0, xA1, xA2, xA3);
        __syncthreads();
        K1_LOADA(kb1, xB0, xB1, xB2, xB3);
        K1_LOADB(kb1, bhB, blB);
        K1_MFMA(0, bhA, blA);
        // ---- tile 2tp+1 (buf 1, cur=B-set, next=A-set)
        K1_STAGE(1, xB0, xB1, xB2, xB3);
        __syncthreads();
        if (tp + 1 < 32) {
            K1_LOADA(kb2, xA0, xA1, xA2, xA3);
            K1_LOADB(kb2, bhA, blA);
        }
        K1_MFMA(1, bhB, blB);
    }

    // ---- epilogue: bias + channel-major float4 stores (m89 C/D mapping)
#pragma unroll
    for (int n = 0; n < 4; ++n) {
        const int col = n0 + wn * 64 + n * 16 + (l & 15);
        const float b = bp[col];
#pragma unroll
        for (int m = 0; m < 4; ++m) {
            const int tok = m0 + wm4 * 16 + m * 16 + (l >> 4) * 4;
            float4 st = { acc[m][n].x + b, acc[m][n].y + b,
                          acc[m][n].z + b, acc[m][n].w + b };
            *(float4*)&hT[(size_t)col * NT + tok] = st;
        }
    }
#undef K1_STAGE_SLOT
#undef K1_STAGE
#undef K1_LOADA
#undef K1_LOADB
#undef K1_MFMA
}

// ---------------------------------------------------------------------------
// K2: per head: hid = relu(h @ W1 + b1); hl = hid @ W2 + b2  (both 64x64 GEMMs)
// Channel-major h_T / hl_T. 256 thr, 128 tokens, one head. Per-thread
// 4e x 8tok; W1/W2 in LDS; hid tile through padded LDS; B-frags = global f4.
// ---------------------------------------------------------------------------
__global__ __launch_bounds__(256) void k2_heads(const float* __restrict__ hT,
                                                const float* __restrict__ W1,
                                                const float* __restrict__ b1,
                                                const float* __restrict__ W2,
                                                const float* __restrict__ b2,
                                                float* __restrict__ hlT)
{
    __shared__ float W1s[64][64];
    __shared__ float W2s[64][64];
    __shared__ float Hs[64][132];     // hid tile [d2][tok], pad 132

    const int t    = threadIdx.x;
    const int eg   = t & 15;          // e-group: e = eg*4 + j
    const int tg   = t >> 4;          // tok-group: tok = tok0 + tg*8 + i
    const int head = blockIdx.y;
    const int tok0 = blockIdx.x * 128;

    {   // stage weights (coalesced float4)
        const float4* g1 = (const float4*)(W1 + (size_t)head * HD * HD);
        const float4* g2 = (const float4*)(W2 + (size_t)head * HD * HD);
        float4* s1 = (float4*)&W1s[0][0];
        float4* s2 = (float4*)&W2s[0][0];
#pragma unroll
        for (int q = 0; q < 4; ++q) {
            s1[t + q * 256] = g1[t + q * 256];
            s2[t + q * 256] = g2[t + q * 256];
        }
    }
    const float4 b1v = *(const float4*)&b1[head * HD + eg * 4];
    const float4 b2v = *(const float4*)&b2[head * HD + eg * 4];
    __syncthreads();

    // ---- stage 1: hid[e][tok] = relu(b1 + sum_d h_T[head*64+d][tok]*W1[d][e])
    float acc[4][8];
    {
        const float bb[4] = { b1v.x, b1v.y, b1v.z, b1v.w };
#pragma unroll
        for (int j = 0; j < 4; ++j)
#pragma unroll
            for (int i = 0; i < 8; ++i) acc[j][i] = bb[j];
    }
    const float* hbase = &hT[(size_t)(head * HD) * NT + tok0 + tg * 8];
#pragma unroll 4
    for (int d = 0; d < HD; ++d) {
        const float4 w  = *(const float4*)&W1s[d][eg * 4];
        const float4 h0 = *(const float4*)&hbase[(size_t)d * NT];
        const float4 h1 = *(const float4*)&hbase[(size_t)d * NT + 4];
        const float wv[4] = { w.x, w.y, w.z, w.w };
        const float hv[8] = { h0.x, h0.y, h0.z, h0.w, h1.x, h1.y, h1.z, h1.w };
#pragma unroll
        for (int j = 0; j < 4; ++j)
#pragma unroll
            for (int i = 0; i < 8; ++i)
                acc[j][i] = fmaf(wv[j], hv[i], acc[j][i]);
    }
#pragma unroll
    for (int j = 0; j < 4; ++j) {
        float4 lo, hi;
        lo.x = fmaxf(acc[j][0], 0.f); lo.y = fmaxf(acc[j][1], 0.f);
        lo.z = fmaxf(acc[j][2], 0.f); lo.w = fmaxf(acc[j][3], 0.f);
        hi.x = fmaxf(acc[j][4], 0.f); hi.y = fmaxf(acc[j][5], 0.f);
        hi.z = fmaxf(acc[j][6], 0.f); hi.w = fmaxf(acc[j][7], 0.f);
        *(float4*)&Hs[eg * 4 + j][tg * 8]     = lo;
        *(float4*)&Hs[eg * 4 + j][tg * 8 + 4] = hi;
    }
    __syncthreads();

    // ---- stage 2: hl[e][tok] = b2 + sum_d2 Hs[d2][tok]*W2[d2][e]
    {
        const float bb[4] = { b2v.x, b2v.y, b2v.z, b2v.w };
#pragma unroll
        for (int j = 0; j < 4; ++j)
#pragma unroll
            for (int i = 0; i < 8; ++i) acc[j][i] = bb[j];
    }
#pragma unroll 4
    for (int d = 0; d < HD; ++d) {
        const float4 w  = *(const float4*)&W2s[d][eg * 4];
        const float4 h0 = *(const float4*)&Hs[d][tg * 8];
        const float4 h1 = *(const float4*)&Hs[d][tg * 8 + 4];
        const float wv[4] = { w.x, w.y, w.z, w.w };
        const float hv[8] = { h0.x, h0.y, h0.z, h0.w, h1.x, h1.y, h1.z, h1.w };
#pragma unroll
        for (int j = 0; j < 4; ++j)
#pragma unroll
            for (int i = 0; i < 8; ++i)
                acc[j][i] = fmaf(wv[j], hv[i], acc[j][i]);
    }
#pragma unroll
    for (int j = 0; j < 4; ++j) {
        float4 lo = { acc[j][0], acc[j][1], acc[j][2], acc[j][3] };
        float4 hi = { acc[j][4], acc[j][5], acc[j][6], acc[j][7] };
        float* dst = &hlT[(size_t)(head * HD + eg * 4 + j) * NT + tok0 + tg * 8];
        *(float4*)&dst[0] = lo;
        *(float4*)&dst[4] = hi;
    }
}

// ---------------------------------------------------------------------------
// K3: gl[tok][e] = (hl_T[:, tok] . Wc[:, e] + bc[e]) / clip(T); top-2 softmax.
// 512 thr, 64 tokens/block, per-thread 4e x 2tok. No LDS; Wc L1/L2-resident.
// ---------------------------------------------------------------------------
__global__ __launch_bounds__(512) void k3_gate(const float* __restrict__ hlT,
                                               const float* __restrict__ Wc,
                                               const float* __restrict__ bc,
                                               const float* __restrict__ temp,
                                               float* __restrict__ out)
{
    const int t    = threadIdx.x;
    const int eg   = t & 15;          // e = eg*4 + j  (low lane bits -> shfl ok)
    const int tg   = t >> 4;          // 0..31: tok = tok0 + tg*2 + i
    const int tok0 = blockIdx.x * 64;

    const float tv  = fminf(fmaxf(temp[0], 0.5f), 5.0f);
    const float inv = 1.0f / tv;      // uniform scale: ordering identical to /tv
    const float4 bcv = *(const float4*)&bc[eg * 4];

    float acc[4][2];
    acc[0][0] = bcv.x; acc[0][1] = bcv.x;
    acc[1][0] = bcv.y; acc[1][1] = bcv.y;
    acc[2][0] = bcv.z; acc[2][1] = bcv.z;
    acc[3][0] = bcv.w; acc[3][1] = bcv.w;

    const float* hb = &hlT[tok0 + tg * 2];
#pragma unroll 8
    for (int k = 0; k < PROJ; ++k) {
        const float2 hv = *(const float2*)&hb[(size_t)k * NT];
        const float4 wv = *(const float4*)&Wc[k * NE + eg * 4];
        const float wa[4] = { wv.x, wv.y, wv.z, wv.w };
#pragma unroll
        for (int j = 0; j < 4; ++j) {
            acc[j][0] = fmaf(wa[j], hv.x, acc[j][0]);
            acc[j][1] = fmaf(wa[j], hv.y, acc[j][1]);
        }
    }

#pragma unroll
    for (int i = 0; i < 2; ++i) {
        const int tok = tok0 + tg * 2 + i;
        float gl_[4];
#pragma unroll
        for (int j = 0; j < 4; ++j) gl_[j] = acc[j][i] * inv;

        // top-1 (strict > keeps lowest index; cross-lane ties -> lower index)
        float v1 = gl_[0]; int i1 = eg * 4;
#pragma unroll
        for (int j = 1; j < 4; ++j)
            if (gl_[j] > v1) { v1 = gl_[j]; i1 = eg * 4 + j; }
#pragma unroll
        for (int off = 8; off >= 1; off >>= 1) {
            const float ov = __shfl_xor(v1, off);
            const int   oi = __shfl_xor(i1, off);
            if (ov > v1 || (ov == v1 && oi < i1)) { v1 = ov; i1 = oi; }
        }
        // top-2: exclude winner
        float v2 = -INFINITY; int i2 = NE;
#pragma unroll
        for (int j = 0; j < 4; ++j) {
            const int e = eg * 4 + j;
            if (e != i1 && gl_[j] > v2) { v2 = gl_[j]; i2 = e; }
        }
#pragma unroll
        for (int off = 8; off >= 1; off >>= 1) {
            const float ov = __shfl_xor(v2, off);
            const int   oi = __shfl_xor(i2, off);
            if (ov > v2 || (ov == v2 && oi < i2)) { v2 = ov; i2 = oi; }
        }

        const float e2  = expf(v2 - v1);
        const float s   = 1.f + e2;
        const float g1v = 1.f / s;
        const float g2v = e2 / s;

        float4 gv;
        {
            const int e0 = eg * 4;
            gv.x = (e0 + 0 == i1) ? g1v : ((e0 + 0 == i2) ? g2v : 0.f);
            gv.y = (e0 + 1 == i1) ? g1v : ((e0 + 1 == i2) ? g2v : 0.f);
            gv.z = (e0 + 2 == i1) ? g1v : ((e0 + 2 == i2) ? g2v : 0.f);
            gv.w = (e0 + 3 == i1) ? g1v : ((e0 + 3 == i2) ? g2v : 0.f);
        }
        *(float4*)&out[GATES_OFF + (size_t)tok * NE + eg * 4] = gv;
        const float4 glv = { gl_[0], gl_[1], gl_[2], gl_[3] };
        *(float4*)&out[GL_OFF + (size_t)tok * NE + eg * 4] = glv;
        if (eg == 0) {
            out[IDX_OFF + (size_t)tok * 2 + 0] = (float)i1;
            out[IDX_OFF + (size_t)tok * 2 + 1] = (float)i2;
        }
    }
}

// ---------------------------------------------------------------------------
extern "C" void kernel_launch(void* const* d_in, const int* in_sizes, int n_in,
                              void* d_out, int out_size, void* d_ws, size_t ws_size,
                              hipStream_t stream)
{
    (void)in_sizes; (void)n_in; (void)out_size; (void)ws_size;

    const float* x    = (const float*)d_in[0];
    const float* Wp   = (const float*)d_in[1];
    const float* bp   = (const float*)d_in[2];
    const float* W1   = (const float*)d_in[3];
    const float* b1   = (const float*)d_in[4];
    const float* W2   = (const float*)d_in[5];
    const float* b2   = (const float*)d_in[6];
    const float* Wc   = (const float*)d_in[7];
    const float* bc   = (const float*)d_in[8];
    const float* temp = (const float*)d_in[9];

    float* out = (float*)d_out;
    float* hT  = (float*)d_ws;                    // [256][16384] f32, 16.8 MB
    float* hlT = hT + (size_t)PROJ * NT;          // [256][16384] f32, 16.8 MB

    // Wp bf16 hi/lo splits live in the hlT region (dead until k2 writes it).
    ushort* WpT_hi = (ushort*)hlT;                // 1 MB
    ushort* WpT_lo = WpT_hi + (size_t)KD * PROJ;  // 1 MB

    k0_split<<<dim3(512),            256, 0, stream>>>(Wp, WpT_hi, WpT_lo);
    k1_mfma <<<dim3(NT / 128, 2),    256, 0, stream>>>(x, WpT_hi, WpT_lo, bp, hT);
    k2_heads<<<dim3(NT / 128, NH),   256, 0, stream>>>(hT, W1, b1, W2, b2, hlT);
    k3_gate <<<dim3(NT / 64),        512, 0, stream>>>(hlT, Wc, bc, temp, out);
}

// Round 9
// 219.537 us; speedup vs baseline: 1.6471x; 1.0464x over previous
//
#include <hip/hip_runtime.h>
#include <math.h>

#define NT   16384
#define KD   2048
#define PROJ 256
#define NH   4
#define HD   64
#define NE   64

#define GATES_OFF 0
#define IDX_OFF   (NT * NE)            // 1048576
#define GL_OFF    (NT * NE + NT * 2)   // 1081344

typedef __attribute__((ext_vector_type(8))) short short8;   // 8 bf16 (4 VGPR)
typedef __attribute__((ext_vector_type(4))) float f32x4;    // MFMA C/D

static __device__ __forceinline__ ushort f2bf_rne(float f) {
    uint u = __float_as_uint(f);
    u += 0x7FFFu + ((u >> 16) & 1u);
    return (ushort)(u >> 16);
}
static __device__ __forceinline__ float bf2f(ushort b) {
    return __uint_as_float(((uint)b) << 16);
}

// ---------------------------------------------------------------------------
// K0: split Wp[k][c] (f32) -> transposed bf16 hi/lo WpT_*[c][k], via LDS-tile
// transpose: coalesced reads AND writes. Grid (32,4) tiles of 64k x 64c.
// ---------------------------------------------------------------------------
__global__ __launch_bounds__(256) void k0_split(const float* __restrict__ Wp,
                                                ushort* __restrict__ WpT_hi,
                                                ushort* __restrict__ WpT_lo)
{
    __shared__ ushort Th[64][72];    // [c][k], row stride 144B (16B-aligned)
    __shared__ ushort Tl[64][72];

    const int t  = threadIdx.x;
    const int kb = blockIdx.x * 64;
    const int cb = blockIdx.y * 64;

    // read 64 rows x 64 cols (f32, coalesced float4), split, scatter to LDS
#pragma unroll
    for (int q = 0; q < 4; ++q) {
        const int s   = t + q * 256;          // 0..1023 float4 slots
        const int row = s >> 4;               // k-row 0..63
        const int c4  = (s & 15) * 4;         // c offset 0..60
        const float4 v = *(const float4*)&Wp[(size_t)(kb + row) * PROJ + cb + c4];
        const float vv[4] = { v.x, v.y, v.z, v.w };
#pragma unroll
        for (int j = 0; j < 4; ++j) {
            const ushort hi = f2bf_rne(vv[j]);
            const ushort lo = f2bf_rne(vv[j] - bf2f(hi));
            Th[c4 + j][row] = hi;
            Tl[c4 + j][row] = lo;
        }
    }
    __syncthreads();

    // write 64 c-rows x 64 k (bf16, coalesced uint4)
#pragma unroll
    for (int q = 0; q < 2; ++q) {
        const int s    = t + q * 256;         // 0..511 uint4 slots
        const int crow = s >> 3;              // 0..63
        const int kq   = (s & 7) * 8;         // 0..56
        *(uint4*)&WpT_hi[(size_t)(cb + crow) * KD + kb + kq] = *(const uint4*)&Th[crow][kq];
        *(uint4*)&WpT_lo[(size_t)(cb + crow) * KD + kb + kq] = *(const uint4*)&Tl[crow][kq];
    }
}

// ---------------------------------------------------------------------------
// K1: h_T = x @ Wp + bp via bf16 split-3 MFMA.
// 128m x 64n tile, BK=32, 256 thr = 4 waves (2x2 -> wave-tile 64x32).
// Grid (128,4) = 512 blocks = 2 blocks/CU (launch_bounds(256,2)): the
// co-resident block's MFMA hides this block's global-load latency.
// A: f32 x -> truncation-split bf16 hi/lo staged in LDS fragment order
//    (conflict-free b128), double-buffered, ONE barrier per k-tile.
// B: pre-split WpT hi/lo (L2-resident) loaded straight to regs, ping-pong.
// 24 MFMA : 8 LDS-b128 per wave per tile.
// ---------------------------------------------------------------------------
__global__ __launch_bounds__(256, 2) void k1_mfma(const float* __restrict__ x,
                                                  const ushort* __restrict__ WpT_hi,
                                                  const ushort* __restrict__ WpT_lo,
                                                  const float* __restrict__ bp,
                                                  float* __restrict__ hT)
{
    __shared__ ushort Ah[2][4096], Al[2][4096];   // 32 KB total

    const int t   = threadIdx.x;
    const int wid = t >> 6;
    const int wm4 = (wid >> 1) * 4;    // wave m-frag base: 0 or 4
    const int wn  = wid & 1;
    const int l   = t & 63;
    const int m0  = blockIdx.x * 128;
    const int n0  = blockIdx.y * 64;

    // A staging slots: thread t handles slots t and t+256 (as R8).
    const int s0 = t, s1 = t + 256;
    const float* xa0 = &x[(size_t)(m0 + 16 * (s0 >> 6) + (s0 & 15)) * KD + ((s0 >> 4) & 3) * 8];
    const float* xa1 = &x[(size_t)(m0 + 16 * (s1 >> 6) + (s1 & 15)) * KD + ((s1 >> 4) & 3) * 8];

    // B fragment base: frag n (0..1) -> col n0 + wn*32 + n*16 + (l&15)
    const ushort* wph = &WpT_hi[(size_t)(n0 + wn * 32 + (l & 15)) * KD + (l >> 4) * 8];
    const ushort* wpl = &WpT_lo[(size_t)(n0 + wn * 32 + (l & 15)) * KD + (l >> 4) * 8];

    f32x4 acc[4][2];
#pragma unroll
    for (int m = 0; m < 4; ++m)
#pragma unroll
        for (int n = 0; n < 2; ++n) acc[m][n] = (f32x4){0.f, 0.f, 0.f, 0.f};

#define K1_STAGE_SLOT(DH, DL, VA, VB)                                          \
    {                                                                          \
        const float ff[8] = { (VA).x, (VA).y, (VA).z, (VA).w,                  \
                              (VB).x, (VB).y, (VB).z, (VB).w };                \
        uint hp[4], lp[4];                                                     \
        _Pragma("unroll")                                                      \
        for (int i = 0; i < 4; ++i) {                                          \
            const uint u0 = __float_as_uint(ff[2 * i]);                        \
            const uint u1 = __float_as_uint(ff[2 * i + 1]);                    \
            hp[i] = (u0 >> 16) | (u1 & 0xFFFF0000u);                           \
            const float r0 = ff[2 * i]     - __uint_as_float(u0 & 0xFFFF0000u);\
            const float r1 = ff[2 * i + 1] - __uint_as_float(u1 & 0xFFFF0000u);\
            lp[i] = (__float_as_uint(r0) >> 16) |                              \
                    (__float_as_uint(r1) & 0xFFFF0000u);                       \
        }                                                                      \
        *(uint4*)(DH) = (uint4){hp[0], hp[1], hp[2], hp[3]};                   \
        *(uint4*)(DL) = (uint4){lp[0], lp[1], lp[2], lp[3]};                   \
    }

#define K1_STAGE(BUF, R0, R1, R2, R3)                                          \
    K1_STAGE_SLOT(&Ah[BUF][s0 * 8], &Al[BUF][s0 * 8], R0, R1);                 \
    K1_STAGE_SLOT(&Ah[BUF][s1 * 8], &Al[BUF][s1 * 8], R2, R3);

#define K1_LOADA(KB, R0, R1, R2, R3)                                           \
    R0 = *(const float4*)(xa0 + (KB));                                         \
    R1 = *(const float4*)(xa0 + (KB) + 4);                                     \
    R2 = *(const float4*)(xa1 + (KB));                                         \
    R3 = *(const float4*)(xa1 + (KB) + 4);

#define K1_LOADB(KB, BH, BL)                                                   \
    _Pragma("unroll")                                                          \
    for (int n = 0; n < 2; ++n) {                                              \
        BH[n] = *(const short8*)(wph + (size_t)n * 16 * KD + (KB));            \
        BL[n] = *(const short8*)(wpl + (size_t)n * 16 * KD + (KB));            \
    }

#define K1_MFMA(BUF, BH, BL)                                                   \
    _Pragma("unroll")                                                          \
    for (int m = 0; m < 4; ++m) {                                              \
        const short8 ah = *(const short8*)&Ah[BUF][((wm4 + m) * 64 + l) * 8];  \
        const short8 al = *(const short8*)&Al[BUF][((wm4 + m) * 64 + l) * 8];  \
        _Pragma("unroll")                                                      \
        for (int n = 0; n < 2; ++n) {                                          \
            acc[m][n] = __builtin_amdgcn_mfma_f32_16x16x32_bf16(ah, BH[n], acc[m][n], 0, 0, 0); \
            acc[m][n] = __builtin_amdgcn_mfma_f32_16x16x32_bf16(ah, BL[n], acc[m][n], 0, 0, 0); \
            acc[m][n] = __builtin_amdgcn_mfma_f32_16x16x32_bf16(al, BH[n], acc[m][n], 0, 0, 0); \
        }                                                                      \
    }

    float4 xA0, xA1, xA2, xA3, xB0, xB1, xB2, xB3;
    short8 bhA[2], blA[2], bhB[2], blB[2];

    K1_LOADA(0, xA0, xA1, xA2, xA3);
    K1_LOADB(0, bhA, blA);

    for (int tp = 0; tp < 32; ++tp) {           // 2 k-tiles per iteration
        const int kb1 = (2 * tp + 1) * 32;
        const int kb2 = (2 * tp + 2) * 32;
        // ---- tile 2tp (buf 0)
        K1_STAGE(0, xA0, xA1, xA2, xA3);
        __syncthreads();
        K1_LOADA(kb1, xB0, xB1, xB2, xB3);
        K1_LOADB(kb1, bhB, blB);
        K1_MFMA(0, bhA, blA);
        // ---- tile 2tp+1 (buf 1)
        K1_STAGE(1, xB0, xB1, xB2, xB3);
        __syncthreads();
        if (tp + 1 < 32) {
            K1_LOADA(kb2, xA0, xA1, xA2, xA3);
            K1_LOADB(kb2, bhA, blA);
        }
        K1_MFMA(1, bhB, blB);
    }

    // ---- epilogue: bias + channel-major float4 stores (m89 C/D mapping)
#pragma unroll
    for (int n = 0; n < 2; ++n) {
        const int col = n0 + wn * 32 + n * 16 + (l & 15);
        const float b = bp[col];
#pragma unroll
        for (int m = 0; m < 4; ++m) {
            const int tok = m0 + wm4 * 16 + m * 16 + (l >> 4) * 4;
            float4 st = { acc[m][n].x + b, acc[m][n].y + b,
                          acc[m][n].z + b, acc[m][n].w + b };
            *(float4*)&hT[(size_t)col * NT + tok] = st;
        }
    }
#undef K1_STAGE_SLOT
#undef K1_STAGE
#undef K1_LOADA
#undef K1_LOADB
#undef K1_MFMA
}

// ---------------------------------------------------------------------------
// K2: per head: hid = relu(h @ W1 + b1); hl = hid @ W2 + b2  (both 64x64 GEMMs)
// Channel-major h_T / hl_T. 256 thr, 128 tokens, one head. Per-thread
// 4e x 8tok; W1/W2 in LDS; hid tile through padded LDS; B-frags = global f4.
// ---------------------------------------------------------------------------
__global__ __launch_bounds__(256) void k2_heads(const float* __restrict__ hT,
                                                const float* __restrict__ W1,
                                                const float* __restrict__ b1,
                                                const float* __restrict__ W2,
                                                const float* __restrict__ b2,
                                                float* __restrict__ hlT)
{
    __shared__ float W1s[64][64];
    __shared__ float W2s[64][64];
    __shared__ float Hs[64][132];     // hid tile [d2][tok], pad 132

    const int t    = threadIdx.x;
    const int eg   = t & 15;          // e-group: e = eg*4 + j
    const int tg   = t >> 4;          // tok-group: tok = tok0 + tg*8 + i
    const int head = blockIdx.y;
    const int tok0 = blockIdx.x * 128;

    {   // stage weights (coalesced float4)
        const float4* g1 = (const float4*)(W1 + (size_t)head * HD * HD);
        const float4* g2 = (const float4*)(W2 + (size_t)head * HD * HD);
        float4* s1 = (float4*)&W1s[0][0];
        float4* s2 = (float4*)&W2s[0][0];
#pragma unroll
        for (int q = 0; q < 4; ++q) {
            s1[t + q * 256] = g1[t + q * 256];
            s2[t + q * 256] = g2[t + q * 256];
        }
    }
    const float4 b1v = *(const float4*)&b1[head * HD + eg * 4];
    const float4 b2v = *(const float4*)&b2[head * HD + eg * 4];
    __syncthreads();

    // ---- stage 1: hid[e][tok] = relu(b1 + sum_d h_T[head*64+d][tok]*W1[d][e])
    float acc[4][8];
    {
        const float bb[4] = { b1v.x, b1v.y, b1v.z, b1v.w };
#pragma unroll
        for (int j = 0; j < 4; ++j)
#pragma unroll
            for (int i = 0; i < 8; ++i) acc[j][i] = bb[j];
    }
    const float* hbase = &hT[(size_t)(head * HD) * NT + tok0 + tg * 8];
#pragma unroll 4
    for (int d = 0; d < HD; ++d) {
        const float4 w  = *(const float4*)&W1s[d][eg * 4];
        const float4 h0 = *(const float4*)&hbase[(size_t)d * NT];
        const float4 h1 = *(const float4*)&hbase[(size_t)d * NT + 4];
        const float wv[4] = { w.x, w.y, w.z, w.w };
        const float hv[8] = { h0.x, h0.y, h0.z, h0.w, h1.x, h1.y, h1.z, h1.w };
#pragma unroll
        for (int j = 0; j < 4; ++j)
#pragma unroll
            for (int i = 0; i < 8; ++i)
                acc[j][i] = fmaf(wv[j], hv[i], acc[j][i]);
    }
#pragma unroll
    for (int j = 0; j < 4; ++j) {
        float4 lo, hi;
        lo.x = fmaxf(acc[j][0], 0.f); lo.y = fmaxf(acc[j][1], 0.f);
        lo.z = fmaxf(acc[j][2], 0.f); lo.w = fmaxf(acc[j][3], 0.f);
        hi.x = fmaxf(acc[j][4], 0.f); hi.y = fmaxf(acc[j][5], 0.f);
        hi.z = fmaxf(acc[j][6], 0.f); hi.w = fmaxf(acc[j][7], 0.f);
        *(float4*)&Hs[eg * 4 + j][tg * 8]     = lo;
        *(float4*)&Hs[eg * 4 + j][tg * 8 + 4] = hi;
    }
    __syncthreads();

    // ---- stage 2: hl[e][tok] = b2 + sum_d2 Hs[d2][tok]*W2[d2][e]
    {
        const float bb[4] = { b2v.x, b2v.y, b2v.z, b2v.w };
#pragma unroll
        for (int j = 0; j < 4; ++j)
#pragma unroll
            for (int i = 0; i < 8; ++i) acc[j][i] = bb[j];
    }
#pragma unroll 4
    for (int d = 0; d < HD; ++d) {
        const float4 w  = *(const float4*)&W2s[d][eg * 4];
        const float4 h0 = *(const float4*)&Hs[d][tg * 8];
        const float4 h1 = *(const float4*)&Hs[d][tg * 8 + 4];
        const float wv[4] = { w.x, w.y, w.z, w.w };
        const float hv[8] = { h0.x, h0.y, h0.z, h0.w, h1.x, h1.y, h1.z, h1.w };
#pragma unroll
        for (int j = 0; j < 4; ++j)
#pragma unroll
            for (int i = 0; i < 8; ++i)
                acc[j][i] = fmaf(wv[j], hv[i], acc[j][i]);
    }
#pragma unroll
    for (int j = 0; j < 4; ++j) {
        float4 lo = { acc[j][0], acc[j][1], acc[j][2], acc[j][3] };
        float4 hi = { acc[j][4], acc[j][5], acc[j][6], acc[j][7] };
        float* dst = &hlT[(size_t)(head * HD + eg * 4 + j) * NT + tok0 + tg * 8];
        *(float4*)&dst[0] = lo;
        *(float4*)&dst[4] = hi;
    }
}

// ---------------------------------------------------------------------------
// K3: gl[tok][e] = (hl_T[:, tok] . Wc[:, e] + bc[e]) / clip(T); top-2 softmax.
// 512 thr, 64 tokens/block, per-thread 4e x 2tok. No LDS; Wc L1/L2-resident.
// ---------------------------------------------------------------------------
__global__ __launch_bounds__(512) void k3_gate(const float* __restrict__ hlT,
                                               const float* __restrict__ Wc,
                                               const float* __restrict__ bc,
                                               const float* __restrict__ temp,
                                               float* __restrict__ out)
{
    const int t    = threadIdx.x;
    const int eg   = t & 15;          // e = eg*4 + j  (low lane bits -> shfl ok)
    const int tg   = t >> 4;          // 0..31: tok = tok0 + tg*2 + i
    const int tok0 = blockIdx.x * 64;

    const float tv  = fminf(fmaxf(temp[0], 0.5f), 5.0f);
    const float inv = 1.0f / tv;      // uniform scale: ordering identical to /tv
    const float4 bcv = *(const float4*)&bc[eg * 4];

    float acc[4][2];
    acc[0][0] = bcv.x; acc[0][1] = bcv.x;
    acc[1][0] = bcv.y; acc[1][1] = bcv.y;
    acc[2][0] = bcv.z; acc[2][1] = bcv.z;
    acc[3][0] = bcv.w; acc[3][1] = bcv.w;

    const float* hb = &hlT[tok0 + tg * 2];
#pragma unroll 8
    for (int k = 0; k < PROJ; ++k) {
        const float2 hv = *(const float2*)&hb[(size_t)k * NT];
        const float4 wv = *(const float4*)&Wc[k * NE + eg * 4];
        const float wa[4] = { wv.x, wv.y, wv.z, wv.w };
#pragma unroll
        for (int j = 0; j < 4; ++j) {
            acc[j][0] = fmaf(wa[j], hv.x, acc[j][0]);
            acc[j][1] = fmaf(wa[j], hv.y, acc[j][1]);
        }
    }

#pragma unroll
    for (int i = 0; i < 2; ++i) {
        const int tok = tok0 + tg * 2 + i;
        float gl_[4];
#pragma unroll
        for (int j = 0; j < 4; ++j) gl_[j] = acc[j][i] * inv;

        // top-1 (strict > keeps lowest index; cross-lane ties -> lower index)
        float v1 = gl_[0]; int i1 = eg * 4;
#pragma unroll
        for (int j = 1; j < 4; ++j)
            if (gl_[j] > v1) { v1 = gl_[j]; i1 = eg * 4 + j; }
#pragma unroll
        for (int off = 8; off >= 1; off >>= 1) {
            const float ov = __shfl_xor(v1, off);
            const int   oi = __shfl_xor(i1, off);
            if (ov > v1 || (ov == v1 && oi < i1)) { v1 = ov; i1 = oi; }
        }
        // top-2: exclude winner
        float v2 = -INFINITY; int i2 = NE;
#pragma unroll
        for (int j = 0; j < 4; ++j) {
            const int e = eg * 4 + j;
            if (e != i1 && gl_[j] > v2) { v2 = gl_[j]; i2 = e; }
        }
#pragma unroll
        for (int off = 8; off >= 1; off >>= 1) {
            const float ov = __shfl_xor(v2, off);
            const int   oi = __shfl_xor(i2, off);
            if (ov > v2 || (ov == v2 && oi < i2)) { v2 = ov; i2 = oi; }
        }

        const float e2  = expf(v2 - v1);
        const float s   = 1.f + e2;
        const float g1v = 1.f / s;
        const float g2v = e2 / s;

        float4 gv;
        {
            const int e0 = eg * 4;
            gv.x = (e0 + 0 == i1) ? g1v : ((e0 + 0 == i2) ? g2v : 0.f);
            gv.y = (e0 + 1 == i1) ? g1v : ((e0 + 1 == i2) ? g2v : 0.f);
            gv.z = (e0 + 2 == i1) ? g1v : ((e0 + 2 == i2) ? g2v : 0.f);
            gv.w = (e0 + 3 == i1) ? g1v : ((e0 + 3 == i2) ? g2v : 0.f);
        }
        *(float4*)&out[GATES_OFF + (size_t)tok * NE + eg * 4] = gv;
        const float4 glv = { gl_[0], gl_[1], gl_[2], gl_[3] };
        *(float4*)&out[GL_OFF + (size_t)tok * NE + eg * 4] = glv;
        if (eg == 0) {
            out[IDX_OFF + (size_t)tok * 2 + 0] = (float)i1;
            out[IDX_OFF + (size_t)tok * 2 + 1] = (float)i2;
        }
    }
}

// ---------------------------------------------------------------------------
extern "C" void kernel_launch(void* const* d_in, const int* in_sizes, int n_in,
                              void* d_out, int out_size, void* d_ws, size_t ws_size,
                              hipStream_t stream)
{
    (void)in_sizes; (void)n_in; (void)out_size; (void)ws_size;

    const float* x    = (const float*)d_in[0];
    const float* Wp   = (const float*)d_in[1];
    const float* bp   = (const float*)d_in[2];
    const float* W1   = (const float*)d_in[3];
    const float* b1   = (const float*)d_in[4];
    const float* W2   = (const float*)d_in[5];
    const float* b2   = (const float*)d_in[6];
    const float* Wc   = (const float*)d_in[7];
    const float* bc   = (const float*)d_in[8];
    const float* temp = (const float*)d_in[9];

    float* out = (float*)d_out;
    float* hT  = (float*)d_ws;                    // [256][16384] f32, 16.8 MB
    float* hlT = hT + (size_t)PROJ * NT;          // [256][16384] f32, 16.8 MB

    // Wp bf16 hi/lo splits live in the hlT region (dead until k2 writes it).
    ushort* WpT_hi = (ushort*)hlT;                // 1 MB
    ushort* WpT_lo = WpT_hi + (size_t)KD * PROJ;  // 1 MB

    k0_split<<<dim3(KD / 64, PROJ / 64), 256, 0, stream>>>(Wp, WpT_hi, WpT_lo);
    k1_mfma <<<dim3(NT / 128, PROJ / 64), 256, 0, stream>>>(x, WpT_hi, WpT_lo, bp, hT);
    k2_heads<<<dim3(NT / 128, NH),        256, 0, stream>>>(hT, W1, b1, W2, b2, hlT);
    k3_gate <<<dim3(NT / 64),             512, 0, stream>>>(hlT, Wc, bc, temp, out);
}